// Round 2
// baseline (993.022 us; speedup 1.0000x reference)
//
#include <hip/hip_runtime.h>

// Problem constants
#define FBANK_MEAN 15.41663f
#define FBANK_STD  6.55582f

constexpr int Bb   = 32;
constexpr int T    = 3200;
constexpr int D    = 128;
constexpr int PATCH = 16;
constexpr int C    = 512;    // embed_dim
constexpr int QD   = 256;    // quant_dim
constexpr int QN   = 1024;   // quant_n
constexpr int Tp   = T / PATCH;   // 200
constexpr int Fp   = D / PATCH;   // 8
constexpr int NTOK = Tp * Fp;     // 1600 tokens per batch
constexpr int TOKS = Bb * NTOK;   // 51200 total tokens
constexpr int TPB  = 8;           // tokens per block (one tp row)

// ---------------------------------------------------------------------------
// Prep 1: transpose conv_w (512 x 256) -> wt (256 x 512) for coalesced reads
__global__ void prep_wt(const float* __restrict__ w, float* __restrict__ wt) {
    int idx = blockIdx.x * 256 + threadIdx.x;   // idx = k*512 + c
    int k = idx >> 9;
    int c = idx & 511;
    wt[idx] = w[c * 256 + k];
}

// Prep 2: l2-normalize codebook rows, store transposed: cbt[d*1024 + k]
__global__ void prep_cb(const float* __restrict__ cb, float* __restrict__ cbt) {
    int k = blockIdx.x;       // code row
    int d = threadIdx.x;      // dim
    float v = cb[k * QD + d];
    float s = v * v;
    #pragma unroll
    for (int off = 32; off >= 1; off >>= 1) s += __shfl_xor(s, off);
    __shared__ float partial[4];
    if ((threadIdx.x & 63) == 0) partial[threadIdx.x >> 6] = s;
    __syncthreads();
    float tot = partial[0] + partial[1] + partial[2] + partial[3];
    float r = rsqrtf(tot + 1e-12f);
    cbt[d * QN + k] = v * r;
}

// ---------------------------------------------------------------------------
// Fused: patch -> conv -> LN -> proj -> l2norm -> sims -> argmax
__global__ __launch_bounds__(256) void fused_tok(
    const float* __restrict__ xs,    // B*T*D
    const float* __restrict__ wt,    // 256 x 512 (k-major)
    const float* __restrict__ proj,  // 512 x 256 (k-major)
    const float* __restrict__ cbt,   // 256 x 1024 (d-major)
    int* __restrict__ out_ind)       // TOKS
{
    __shared__ float patch[TPB * 256];     // 8 KB; later reused for xp
    __shared__ float feats[TPB * C];       // 16 KB
    __shared__ float mu_s[TPB], rs_s[TPB];
    __shared__ float rvs[4][TPB];
    __shared__ int   ris[4][TPB];

    const int tid = threadIdx.x;
    const int g0  = blockIdx.x * TPB;       // first global token
    const int b   = g0 / NTOK;
    const int n0  = g0 - b * NTOK;          // tp*8 (block == one tp row)
    const int tp  = n0 >> 3;

    // ---- 1. load 8 patches (16 rows x 128 cols, fully contiguous rows) ----
    const float* xrow = xs + ((size_t)b * T + (size_t)tp * PATCH) * D;
    const float inv = 1.0f / (2.0f * FBANK_STD);
    #pragma unroll
    for (int r = 0; r < 8; ++r) {
        int flat = r * 256 + tid;           // 0..2047
        int i = flat >> 7;                  // patch row 0..15
        int d = flat & 127;                 // fbank col
        float v = (xrow[i * D + d] - FBANK_MEAN) * inv;
        patch[(d >> 4) * 256 + i * 16 + (d & 15)] = v;   // [tok=fp][k=i*16+j]
    }
    __syncthreads();

    // ---- 2. conv: thread handles channels 2*tid, 2*tid+1 for all 8 toks ----
    float acc0[TPB], acc1[TPB];
    #pragma unroll
    for (int t = 0; t < TPB; ++t) { acc0[t] = 0.f; acc1[t] = 0.f; }
    const float2* wt2 = (const float2*)wt;
    for (int k4 = 0; k4 < 64; ++k4) {
        float4 pv[TPB];
        #pragma unroll
        for (int t = 0; t < TPB; ++t)
            pv[t] = *(const float4*)&patch[t * 256 + k4 * 4];
        #pragma unroll
        for (int kk = 0; kk < 4; ++kk) {
            float2 w = wt2[(k4 * 4 + kk) * 256 + tid];
            #pragma unroll
            for (int t = 0; t < TPB; ++t) {
                float p = ((const float*)&pv[t])[kk];
                acc0[t] += p * w.x;
                acc1[t] += p * w.y;
            }
        }
    }
    #pragma unroll
    for (int t = 0; t < TPB; ++t) {
        feats[t * C + 2 * tid]     = acc0[t];
        feats[t * C + 2 * tid + 1] = acc1[t];
    }
    __syncthreads();

    // ---- 3. LayerNorm over C=512 per token (32 lanes per token) ----
    {
        int w = tid >> 6, h = (tid >> 5) & 1, l = tid & 31;
        int t = w * 2 + h;
        float s1 = 0.f, s2 = 0.f;
        #pragma unroll
        for (int m = 0; m < 16; ++m) {
            float v = feats[t * C + l + m * 32];
            s1 += v; s2 += v * v;
        }
        #pragma unroll
        for (int off = 16; off >= 1; off >>= 1) {
            s1 += __shfl_xor(s1, off);
            s2 += __shfl_xor(s2, off);
        }
        if (l == 0) {
            float mu  = s1 * (1.0f / 512.0f);
            float var = s2 * (1.0f / 512.0f) - mu * mu;
            mu_s[t] = mu;
            rs_s[t] = rsqrtf(var + 1e-5f);
        }
    }
    __syncthreads();
    #pragma unroll
    for (int m = 0; m < 16; ++m) {
        int flat = m * 256 + tid;
        int t = flat >> 9;
        feats[flat] = (feats[flat] - mu_s[t]) * rs_s[t];
    }
    __syncthreads();

    // ---- 4. xp[t][tid] = sum_k feats[t][k] * proj[k][tid] ----
    float xpv[TPB];
    #pragma unroll
    for (int t = 0; t < TPB; ++t) xpv[t] = 0.f;
    for (int k4 = 0; k4 < 128; ++k4) {
        float4 fv[TPB];
        #pragma unroll
        for (int t = 0; t < TPB; ++t)
            fv[t] = *(const float4*)&feats[t * C + k4 * 4];
        #pragma unroll
        for (int kk = 0; kk < 4; ++kk) {
            float p = proj[(k4 * 4 + kk) * QD + tid];
            #pragma unroll
            for (int t = 0; t < TPB; ++t)
                xpv[t] += ((const float*)&fv[t])[kk] * p;
        }
    }
    // l2norm of xp rows; xp lives in the patch LDS region (done with patches)
    float* xp = patch;
    #pragma unroll
    for (int t = 0; t < TPB; ++t) xp[t * 256 + tid] = xpv[t];
    __syncthreads();
    {
        int w = tid >> 6, h = (tid >> 5) & 1, l = tid & 31;
        int t = w * 2 + h;
        float s = 0.f;
        #pragma unroll
        for (int m = 0; m < 8; ++m) {
            float v = xp[t * 256 + l + m * 32];
            s += v * v;
        }
        #pragma unroll
        for (int off = 16; off >= 1; off >>= 1) s += __shfl_xor(s, off);
        if (l == 0) rs_s[t] = rsqrtf(s + 1e-12f);
    }
    __syncthreads();
    #pragma unroll
    for (int m = 0; m < 8; ++m) {
        int flat = m * 256 + tid;
        int t = flat >> 8;
        xp[flat] *= rs_s[t];
    }
    __syncthreads();

    // ---- 5. sims: thread handles codes tid, tid+256, tid+512, tid+768 ----
    float sim[4][TPB];
    #pragma unroll
    for (int cc = 0; cc < 4; ++cc)
        #pragma unroll
        for (int t = 0; t < TPB; ++t) sim[cc][t] = 0.f;
    for (int d4 = 0; d4 < 64; ++d4) {
        float4 xv[TPB];
        #pragma unroll
        for (int t = 0; t < TPB; ++t)
            xv[t] = *(const float4*)&xp[t * 256 + d4 * 4];
        #pragma unroll
        for (int dd = 0; dd < 4; ++dd) {
            int d = d4 * 4 + dd;
            float cb0 = cbt[d * QN + tid];
            float cb1 = cbt[d * QN + tid + 256];
            float cb2 = cbt[d * QN + tid + 512];
            float cb3 = cbt[d * QN + tid + 768];
            #pragma unroll
            for (int t = 0; t < TPB; ++t) {
                float x = ((const float*)&xv[t])[dd];
                sim[0][t] += x * cb0;
                sim[1][t] += x * cb1;
                sim[2][t] += x * cb2;
                sim[3][t] += x * cb3;
            }
        }
    }

    // ---- 6. argmax per token (first-max tie-break = smallest index) ----
    #pragma unroll
    for (int t = 0; t < TPB; ++t) {
        float bv = sim[0][t];
        int   bi = tid;
        #pragma unroll
        for (int cc = 1; cc < 4; ++cc) {
            float v = sim[cc][t];
            int   i = tid + 256 * cc;
            if (v > bv) { bv = v; bi = i; }   // strict > keeps smaller index
        }
        #pragma unroll
        for (int off = 32; off >= 1; off >>= 1) {
            float ov = __shfl_xor(bv, off);
            int   oi = __shfl_xor(bi, off);
            if (ov > bv || (ov == bv && oi < bi)) { bv = ov; bi = oi; }
        }
        if ((tid & 63) == 0) { rvs[tid >> 6][t] = bv; ris[tid >> 6][t] = bi; }
    }
    __syncthreads();
    if (tid < TPB) {
        int t = tid;
        float bv = rvs[0][t];
        int   bi = ris[0][t];
        #pragma unroll
        for (int w = 1; w < 4; ++w) {
            float ov = rvs[w][t];
            int   oi = ris[w][t];
            if (ov > bv || (ov == bv && oi < bi)) { bv = ov; bi = oi; }
        }
        out_ind[g0 + t] = bi;
    }
}

// ---------------------------------------------------------------------------
// embed_len[b] = 8 * min(200, ilens[b] >> 4)
__global__ void len_kernel(const int* __restrict__ ilens, int* __restrict__ out_len) {
    int b = threadIdx.x;
    if (b < Bb) {
        int il = ilens[b];
        int cnt = il >> 4;
        if (cnt > Tp) cnt = Tp;
        if (cnt < 0) cnt = 0;
        out_len[b] = Fp * cnt;
    }
}

// ---------------------------------------------------------------------------
extern "C" void kernel_launch(void* const* d_in, const int* in_sizes, int n_in,
                              void* d_out, int out_size, void* d_ws, size_t ws_size,
                              hipStream_t stream) {
    const float* xs       = (const float*)d_in[0];   // (32,3200,128) f32
    const int*   ilens    = (const int*)  d_in[1];   // (32,) i32
    const float* conv_w   = (const float*)d_in[2];   // (512,1,16,16) f32
    const float* proj     = (const float*)d_in[3];   // (512,256) f32
    const float* codebook = (const float*)d_in[4];   // (1024,256) f32
    int* out = (int*)d_out;                          // 51200 ind + 32 len

    float* wt  = (float*)d_ws;            // 256x512 = 512 KB
    float* cbt = wt + C * 256;            // 256x1024 = 1 MB

    prep_wt<<<C * 256 / 256, 256, 0, stream>>>(conv_w, wt);
    prep_cb<<<QN, QD, 0, stream>>>(codebook, cbt);
    fused_tok<<<TOKS / TPB, 256, 0, stream>>>(xs, wt, proj, cbt, out);
    len_kernel<<<1, 64, 0, stream>>>(ilens, out + TOKS);
}

// Round 3
// 865.855 us; speedup vs baseline: 1.1469x; 1.1469x over previous
//
#include <hip/hip_runtime.h>

#define FBANK_MEAN 15.41663f
#define FBANK_STD  6.55582f

constexpr int Bb   = 32;
constexpr int T    = 3200;
constexpr int D    = 128;
constexpr int C    = 512;    // embed_dim
constexpr int QD   = 256;    // quant_dim
constexpr int QN   = 1024;   // quant_n
constexpr int Tp   = 200;
constexpr int Fp   = 8;
constexpr int NTOK = Tp * Fp;     // 1600 tokens per batch
constexpr int TOKS = Bb * NTOK;   // 51200
constexpr int TPB  = 16;          // tokens per block (two tp rows)

#define F4(p) (*(const float4*)(p))
#define GETC(v,KK) ((KK)==0?(v).x:((KK)==1?(v).y:((KK)==2?(v).z:(v).w)))

__device__ __forceinline__ void fma4(float4& a, float s, const float4& w) {
    a.x += s * w.x; a.y += s * w.y; a.z += s * w.z; a.w += s * w.w;
}

// ---------------------------------------------------------------------------
// Prep 1: transpose conv_w (512 x 256) -> wt (256 x 512), k-major
__global__ void prep_wt(const float* __restrict__ w, float* __restrict__ wt) {
    int idx = blockIdx.x * 256 + threadIdx.x;   // idx = k*512 + c
    int k = idx >> 9;
    int c = idx & 511;
    wt[idx] = w[c * 256 + k];
}

// Prep 2: l2-normalize codebook rows, store transposed: cbt[d*1024 + k]
__global__ void prep_cb(const float* __restrict__ cb, float* __restrict__ cbt) {
    int k = blockIdx.x;       // code row
    int d = threadIdx.x;      // dim
    float v = cb[k * QD + d];
    float s = v * v;
    #pragma unroll
    for (int off = 32; off >= 1; off >>= 1) s += __shfl_xor(s, off);
    __shared__ float part[4];
    if ((threadIdx.x & 63) == 0) part[threadIdx.x >> 6] = s;
    __syncthreads();
    float tot = part[0] + part[1] + part[2] + part[3];
    cbt[d * QN + k] = v * rsqrtf(tot + 1e-12f);
}

// ---------------------------------------------------------------------------
// Fused: patch -> conv -> LN -> proj -> l2norm -> sims -> argmax
// Thread layout per phase chosen so every LDS token-read is a wave-uniform
// broadcast (wave index == token-group) and register tiles give each loaded
// operand >=4-8 FMAs of reuse.
__global__ __launch_bounds__(256, 3) void fused_tok(
    const float* __restrict__ xs,    // B*T*D
    const float* __restrict__ wt,    // 256 x 512 (k-major)
    const float* __restrict__ proj,  // 512 x 256 (k-major)
    const float* __restrict__ cbt,   // 256 x 1024 (d-major)
    int* __restrict__ out_ind)       // TOKS
{
    __shared__ __align__(16) float patch[TPB * 256];   // 16 KB; reused as xp
    __shared__ __align__(16) float feats[TPB * 512];   // 32 KB
    __shared__ float rv[4][8];
    __shared__ int   ri[4][8];

    const int tid = threadIdx.x;
    const int g0  = blockIdx.x * TPB;
    const int b   = g0 / NTOK;
    const int n0  = g0 - b * NTOK;
    const int tp0 = n0 >> 3;                 // first of the two tp rows

    // ---- 1. patch load: 32 time-rows x 128 cols, contiguous 16 KB --------
    {
        const float4* src = (const float4*)(xs + ((size_t)b * T + (size_t)tp0 * 16) * D);
        const float inv = 1.0f / (2.0f * FBANK_STD);
        #pragma unroll
        for (int r = 0; r < 4; ++r) {
            int f4 = r * 256 + tid;          // float4 index 0..1023
            float4 v = src[f4];
            v.x = (v.x - FBANK_MEAN) * inv;
            v.y = (v.y - FBANK_MEAN) * inv;
            v.z = (v.z - FBANK_MEAN) * inv;
            v.w = (v.w - FBANK_MEAN) * inv;
            int i = f4 >> 5;                 // time row 0..31
            int d = (f4 & 31) << 2;          // fbank col 0..124
            int t = ((i >> 4) << 3) + (d >> 4);
            int k = ((i & 15) << 4) + (d & 15);
            *(float4*)&patch[t * 256 + k] = v;
        }
    }
    __syncthreads();

    // ---- 2. conv GEMM: tile 4 tok x 8 ch per thread, K=256 ---------------
    {
        const int cg = tid & 63;             // channels 8cg..8cg+7
        const int tg = tid >> 6;             // tokens 4tg..4tg+3 (== wave id)
        float4 ca[4], cb4[4];
        #pragma unroll
        for (int j = 0; j < 4; ++j) {
            ca[j]  = make_float4(0.f, 0.f, 0.f, 0.f);
            cb4[j] = make_float4(0.f, 0.f, 0.f, 0.f);
        }
        const float* pbase = &patch[(4 * tg) * 256];
        const float* wbase = &wt[8 * cg];
        for (int k4 = 0; k4 < 64; ++k4) {
            float4 pv[4];
            #pragma unroll
            for (int j = 0; j < 4; ++j)      // wave-uniform broadcast reads
                pv[j] = F4(pbase + j * 256 + k4 * 4);
            #pragma unroll
            for (int kk = 0; kk < 4; ++kk) {
                int k = k4 * 4 + kk;
                float4 w0 = F4(wbase + k * 512);
                float4 w1 = F4(wbase + k * 512 + 4);
                #pragma unroll
                for (int j = 0; j < 4; ++j) {
                    float p = GETC(pv[j], kk);
                    fma4(ca[j],  p, w0);
                    fma4(cb4[j], p, w1);
                }
            }
        }
        #pragma unroll
        for (int j = 0; j < 4; ++j) {
            *(float4*)&feats[(4 * tg + j) * 512 + 8 * cg]     = ca[j];
            *(float4*)&feats[(4 * tg + j) * 512 + 8 * cg + 4] = cb4[j];
        }
    }
    __syncthreads();

    // ---- 3. LayerNorm in place: 16 lanes per token -----------------------
    {
        const int t = tid >> 4, l = tid & 15;
        float s1 = 0.f, s2 = 0.f;
        #pragma unroll
        for (int m = 0; m < 32; ++m) {
            float v = feats[t * 512 + l + 16 * m];
            s1 += v; s2 += v * v;
        }
        #pragma unroll
        for (int off = 8; off >= 1; off >>= 1) {
            s1 += __shfl_xor(s1, off);
            s2 += __shfl_xor(s2, off);
        }
        float mu = s1 * (1.0f / 512.0f);
        float rs = rsqrtf(s2 * (1.0f / 512.0f) - mu * mu + 1e-5f);
        #pragma unroll
        for (int m = 0; m < 32; ++m) {
            int idx = t * 512 + l + 16 * m;
            feats[idx] = (feats[idx] - mu) * rs;
        }
    }
    __syncthreads();

    // ---- 4. proj GEMM: tile 4 tok x 4 qd per thread, K=512 ---------------
    {
        const int qg = tid & 63;             // qd 4qg..4qg+3
        const int tg = tid >> 6;             // tokens 4tg..4tg+3 (== wave id)
        float4 pa[4];
        #pragma unroll
        for (int j = 0; j < 4; ++j) pa[j] = make_float4(0.f, 0.f, 0.f, 0.f);
        const float* fbase = &feats[(4 * tg) * 512];
        const float* pjbase = &proj[4 * qg];
        for (int k4 = 0; k4 < 128; ++k4) {
            float4 fv[4];
            #pragma unroll
            for (int j = 0; j < 4; ++j)      // broadcast reads
                fv[j] = F4(fbase + j * 512 + k4 * 4);
            #pragma unroll
            for (int kk = 0; kk < 4; ++kk) {
                float4 w = F4(pjbase + (k4 * 4 + kk) * 256);
                #pragma unroll
                for (int j = 0; j < 4; ++j)
                    fma4(pa[j], GETC(fv[j], kk), w);
            }
        }
        // patch region is dead (conv consumed it before the post-conv sync)
        #pragma unroll
        for (int j = 0; j < 4; ++j)
            *(float4*)&patch[(4 * tg + j) * 256 + 4 * qg] = pa[j];
    }
    __syncthreads();

    // ---- 5. l2norm xp in place: 16 lanes per token -----------------------
    {
        const int t = tid >> 4, l = tid & 15;
        float s = 0.f;
        #pragma unroll
        for (int m = 0; m < 16; ++m) {
            float v = patch[t * 256 + l + 16 * m];
            s += v * v;
        }
        #pragma unroll
        for (int off = 8; off >= 1; off >>= 1) s += __shfl_xor(s, off);
        float rs = rsqrtf(s + 1e-12f);
        #pragma unroll
        for (int m = 0; m < 16; ++m)
            patch[t * 256 + l + 16 * m] *= rs;
    }
    __syncthreads();

    // ---- 6. sims: tile 8 tok x 8 codes per thread, K=256; then argmax ----
    {
        const int cg = tid & 127;            // codes 8cg..8cg+7
        const int tg = tid >> 7;             // tokens 8tg..8tg+7 (wave-uniform)
        float4 sa[8], sb[8];
        #pragma unroll
        for (int j = 0; j < 8; ++j) {
            sa[j] = make_float4(0.f, 0.f, 0.f, 0.f);
            sb[j] = make_float4(0.f, 0.f, 0.f, 0.f);
        }
        const float* xbase = &patch[(8 * tg) * 256];
        const float* cbase = &cbt[8 * cg];
        for (int d4 = 0; d4 < 64; ++d4) {
            float4 xv[8];
            #pragma unroll
            for (int j = 0; j < 8; ++j)      // broadcast reads
                xv[j] = F4(xbase + j * 256 + d4 * 4);
            #pragma unroll
            for (int dd = 0; dd < 4; ++dd) {
                int d = d4 * 4 + dd;
                float4 c0 = F4(cbase + d * 1024);
                float4 c1 = F4(cbase + d * 1024 + 4);
                #pragma unroll
                for (int j = 0; j < 8; ++j) {
                    float x = GETC(xv[j], dd);
                    fma4(sa[j], x, c0);
                    fma4(sb[j], x, c1);
                }
            }
        }
        // per-thread argmax over its 8 codes (ascending -> strict > keeps lowest)
        const int base = 8 * cg;
        #pragma unroll
        for (int j = 0; j < 8; ++j) {
            float bv = sa[j].x; int bi = base;
            if (sa[j].y > bv) { bv = sa[j].y; bi = base + 1; }
            if (sa[j].z > bv) { bv = sa[j].z; bi = base + 2; }
            if (sa[j].w > bv) { bv = sa[j].w; bi = base + 3; }
            if (sb[j].x > bv) { bv = sb[j].x; bi = base + 4; }
            if (sb[j].y > bv) { bv = sb[j].y; bi = base + 5; }
            if (sb[j].z > bv) { bv = sb[j].z; bi = base + 6; }
            if (sb[j].w > bv) { bv = sb[j].w; bi = base + 7; }
            #pragma unroll
            for (int off = 32; off >= 1; off >>= 1) {
                float ov = __shfl_xor(bv, off);
                int   oi = __shfl_xor(bi, off);
                if (ov > bv || (ov == bv && oi < bi)) { bv = ov; bi = oi; }
            }
            if ((tid & 63) == 0) { rv[tid >> 6][j] = bv; ri[tid >> 6][j] = bi; }
        }
    }
    __syncthreads();
    if (tid < TPB) {
        int t = tid;
        int w0 = (t >> 3) * 2, j = t & 7;    // waves {0,1} own tok 0-7, {2,3} own 8-15
        float v0 = rv[w0][j], v1 = rv[w0 + 1][j];
        int   i0 = ri[w0][j], i1 = ri[w0 + 1][j];
        int bi = (v1 > v0 || (v1 == v0 && i1 < i0)) ? i1 : i0;
        out_ind[g0 + t] = bi;
    }
}

// ---------------------------------------------------------------------------
// embed_len[b] = 8 * min(200, ilens[b] >> 4)
__global__ void len_kernel(const int* __restrict__ ilens, int* __restrict__ out_len) {
    int b = threadIdx.x;
    if (b < Bb) {
        int il = ilens[b];
        int cnt = il >> 4;
        if (cnt > Tp) cnt = Tp;
        if (cnt < 0) cnt = 0;
        out_len[b] = Fp * cnt;
    }
}

// ---------------------------------------------------------------------------
extern "C" void kernel_launch(void* const* d_in, const int* in_sizes, int n_in,
                              void* d_out, int out_size, void* d_ws, size_t ws_size,
                              hipStream_t stream) {
    const float* xs       = (const float*)d_in[0];   // (32,3200,128) f32
    const int*   ilens    = (const int*)  d_in[1];   // (32,) i32
    const float* conv_w   = (const float*)d_in[2];   // (512,1,16,16) f32
    const float* proj     = (const float*)d_in[3];   // (512,256) f32
    const float* codebook = (const float*)d_in[4];   // (1024,256) f32
    int* out = (int*)d_out;                          // 51200 ind + 32 len

    float* wt  = (float*)d_ws;            // 256x512 = 512 KB
    float* cbt = wt + 256 * C;            // 256x1024 = 1 MB

    prep_wt<<<C * 256 / 256, 256, 0, stream>>>(conv_w, wt);
    prep_cb<<<QN, QD, 0, stream>>>(codebook, cbt);
    fused_tok<<<TOKS / TPB, 256, 0, stream>>>(xs, wt, proj, cbt, out);
    len_kernel<<<1, 64, 0, stream>>>(ilens, out + TOKS);
}

// Round 4
// 790.118 us; speedup vs baseline: 1.2568x; 1.0959x over previous
//
#include <hip/hip_runtime.h>

#define FBANK_MEAN 15.41663f
#define FBANK_STD  6.55582f

constexpr int Bb   = 32;
constexpr int T    = 3200;
constexpr int D    = 128;
constexpr int C    = 512;    // embed_dim
constexpr int QD   = 256;    // quant_dim
constexpr int QN   = 1024;   // quant_n
constexpr int Tp   = 200;
constexpr int Fp   = 8;
constexpr int NTOK = Tp * Fp;     // 1600 tokens per batch
constexpr int TOKS = Bb * NTOK;   // 51200
constexpr int TPB  = 16;          // tokens per block (two tp rows)

#define F4(p) (*(const float4*)(p))

__device__ __forceinline__ void fma4(float4& a, float s, const float4& w) {
    a.x += s * w.x; a.y += s * w.y; a.z += s * w.z; a.w += s * w.w;
}

// ---------------------------------------------------------------------------
// Prep 1: transpose conv_w (512 x 256) -> wt (256 x 512), k-major
__global__ void prep_wt(const float* __restrict__ w, float* __restrict__ wt) {
    int idx = blockIdx.x * 256 + threadIdx.x;   // idx = k*512 + c
    int k = idx >> 9;
    int c = idx & 511;
    wt[idx] = w[c * 256 + k];
}

// Prep 2: l2-normalize codebook rows, store transposed: cbt[d*1024 + k]
__global__ void prep_cb(const float* __restrict__ cb, float* __restrict__ cbt) {
    int k = blockIdx.x;       // code row
    int d = threadIdx.x;      // dim
    float v = cb[k * QD + d];
    float s = v * v;
    #pragma unroll
    for (int off = 32; off >= 1; off >>= 1) s += __shfl_xor(s, off);
    __shared__ float part[4];
    if ((threadIdx.x & 63) == 0) part[threadIdx.x >> 6] = s;
    __syncthreads();
    float tot = part[0] + part[1] + part[2] + part[3];
    cbt[d * QN + k] = v * rsqrtf(tot + 1e-12f);
}

// Prep 3: column sums of proj: s[q] = sum_k proj[k][q]  (for LN mean folding)
__global__ void prep_s(const float* __restrict__ proj, float* __restrict__ s) {
    int q = threadIdx.x;
    float acc = 0.f;
    for (int k = 0; k < C; ++k) acc += proj[k * QD + q];
    s[q] = acc;
}

// ---------------------------------------------------------------------------
// Fused: patch -> conv -> (mu) -> proj(-mu*s) -> sims -> argmax
// LN's rsqrt(var) scaling and xp l2norm are per-token positive scalars ->
// argmax-invariant -> eliminated. Mean subtraction folded into proj epilogue.
// Register tiles sized so each wave streams <=256KB of weights per phase
// (L2 traffic ~2.5MB/block vs 8MB in the previous version).
__global__ __launch_bounds__(256, 3) void fused_tok(
    const float* __restrict__ xs,    // B*T*D
    const float* __restrict__ wt,    // 256 x 512 (k-major)
    const float* __restrict__ proj,  // 512 x 256 (k-major)
    const float* __restrict__ cbt,   // 256 x 1024 (d-major, rows l2-normed)
    const float* __restrict__ sv,    // 256 colsum(proj)
    int* __restrict__ out_ind)       // TOKS
{
    __shared__ __align__(16) float patch[TPB * 256];   // 16 KB; reused as xp
    __shared__ __align__(16) float feats[TPB * 512];   // 32 KB
    __shared__ float mu_s[TPB];
    __shared__ float rv[4][TPB];
    __shared__ int   ri[4][TPB];

    const int tid  = threadIdx.x;
    const int lane = tid & 63;
    const int wv   = tid >> 6;               // wave id 0..3
    const int g0   = blockIdx.x * TPB;
    const int b    = g0 / NTOK;
    const int n0   = g0 - b * NTOK;
    const int tp0  = n0 >> 3;                // first of the two tp rows

    // ---- 1. patch staging: 32 time-rows x 128 cols -> patch[t][k] --------
    {
        const float4* src = (const float4*)(xs + ((size_t)b * T + (size_t)tp0 * 16) * D);
        const float inv = 1.0f / (2.0f * FBANK_STD);
        #pragma unroll
        for (int r = 0; r < 4; ++r) {
            int f4 = r * 256 + tid;          // float4 index 0..1023
            float4 v = src[f4];
            v.x = (v.x - FBANK_MEAN) * inv;
            v.y = (v.y - FBANK_MEAN) * inv;
            v.z = (v.z - FBANK_MEAN) * inv;
            v.w = (v.w - FBANK_MEAN) * inv;
            int i = f4 >> 5;                 // time row 0..31
            int d = (f4 & 31) << 2;          // fbank col
            int t = ((i >> 4) << 3) + (d >> 4);
            int k = ((i & 15) << 4) + (d & 15);
            *(float4*)&patch[t * 256 + k] = v;
        }
    }
    __syncthreads();

    // ---- 2. conv: Mr=16 tok x Nr=4 ch; waves = (ch-half, K-half) ---------
    {
        const int c = wv & 1;                // channel half
        const int h = wv >> 1;               // K half
        float4 acc[16];
        #pragma unroll
        for (int j = 0; j < 16; ++j) acc[j] = make_float4(0.f, 0.f, 0.f, 0.f);
        const float* wb = wt + c * 256 + 4 * lane;
        for (int k4 = 0; k4 < 32; ++k4) {
            const int kb = h * 128 + k4 * 4;
            float4 w0 = F4(wb + (kb + 0) * 512);
            float4 w1 = F4(wb + (kb + 1) * 512);
            float4 w2 = F4(wb + (kb + 2) * 512);
            float4 w3 = F4(wb + (kb + 3) * 512);
            #pragma unroll
            for (int hh = 0; hh < 2; ++hh) {   // token subgroups of 8 (reg cap)
                float4 xv[8];
                #pragma unroll
                for (int j = 0; j < 8; ++j)    // wave-uniform broadcasts
                    xv[j] = F4(patch + (hh * 8 + j) * 256 + kb);
                #pragma unroll
                for (int j = 0; j < 8; ++j) {
                    fma4(acc[hh * 8 + j], xv[j].x, w0);
                    fma4(acc[hh * 8 + j], xv[j].y, w1);
                    fma4(acc[hh * 8 + j], xv[j].z, w2);
                    fma4(acc[hh * 8 + j], xv[j].w, w3);
                }
            }
        }
        float* fb = &feats[c * 256 + 4 * lane];
        if (h == 0) {
            #pragma unroll
            for (int j = 0; j < 16; ++j)
                *(float4*)(fb + j * 512) = acc[j];
        }
        __syncthreads();
        if (h == 1) {
            #pragma unroll
            for (int j = 0; j < 16; ++j) {
                float4 o = F4(fb + j * 512);
                o.x += acc[j].x; o.y += acc[j].y; o.z += acc[j].z; o.w += acc[j].w;
                *(float4*)(fb + j * 512) = o;
            }
        }
    }
    __syncthreads();

    // ---- 3. per-token mean of feats (rsqrt(var) scaling dropped) ---------
    {
        const int t = tid >> 4, l = tid & 15;
        float s1 = 0.f;
        #pragma unroll
        for (int m = 0; m < 32; ++m) s1 += feats[t * 512 + l + 16 * m];
        #pragma unroll
        for (int off = 8; off >= 1; off >>= 1) s1 += __shfl_xor(s1, off);
        if (l == 0) mu_s[t] = s1 * (1.0f / 512.0f);
    }
    __syncthreads();

    // ---- 4. proj: Mr=8 tok x Nr=4 qd; waves = (tok-half, K-half) ---------
    {
        const int g = wv & 1;                // token half
        const int h = wv >> 1;               // K half (256 each)
        float4 acc[8];
        #pragma unroll
        for (int j = 0; j < 8; ++j) acc[j] = make_float4(0.f, 0.f, 0.f, 0.f);
        const float* pb = proj + 4 * lane;
        const float* fb = &feats[(g * 8) * 512];
        for (int k4 = 0; k4 < 64; ++k4) {
            const int kb = h * 256 + k4 * 4;
            float4 w0 = F4(pb + (kb + 0) * 256);
            float4 w1 = F4(pb + (kb + 1) * 256);
            float4 w2 = F4(pb + (kb + 2) * 256);
            float4 w3 = F4(pb + (kb + 3) * 256);
            float4 xv[8];
            #pragma unroll
            for (int j = 0; j < 8; ++j)        // broadcasts
                xv[j] = F4(fb + j * 512 + kb);
            #pragma unroll
            for (int j = 0; j < 8; ++j) {
                fma4(acc[j], xv[j].x, w0);
                fma4(acc[j], xv[j].y, w1);
                fma4(acc[j], xv[j].z, w2);
                fma4(acc[j], xv[j].w, w3);
            }
        }
        float* xb = &patch[(g * 8) * 256 + 4 * lane];   // patch region = xp now
        if (h == 0) {                        // epilogue: y - mu * colsum(proj)
            float4 s4 = F4(sv + 4 * lane);
            #pragma unroll
            for (int j = 0; j < 8; ++j) {
                float mu = mu_s[g * 8 + j];
                float4 o;
                o.x = acc[j].x - mu * s4.x;
                o.y = acc[j].y - mu * s4.y;
                o.z = acc[j].z - mu * s4.z;
                o.w = acc[j].w - mu * s4.w;
                *(float4*)(xb + j * 256) = o;
            }
        }
        __syncthreads();
        if (h == 1) {
            #pragma unroll
            for (int j = 0; j < 8; ++j) {
                float4 o = F4(xb + j * 256);
                o.x += acc[j].x; o.y += acc[j].y; o.z += acc[j].z; o.w += acc[j].w;
                *(float4*)(xb + j * 256) = o;
            }
        }
    }
    __syncthreads();

    // ---- 5. sims: Mr=16 tok x Nr=4 codes; waves = code-quarters ----------
    {
        const int cq = wv;                   // code quarter
        float4 acc[16];
        #pragma unroll
        for (int j = 0; j < 16; ++j) acc[j] = make_float4(0.f, 0.f, 0.f, 0.f);
        const float* cbase = cbt + cq * 256 + 4 * lane;
        for (int d4 = 0; d4 < 64; ++d4) {
            const int db = d4 * 4;
            float4 w0 = F4(cbase + (db + 0) * 1024);
            float4 w1 = F4(cbase + (db + 1) * 1024);
            float4 w2 = F4(cbase + (db + 2) * 1024);
            float4 w3 = F4(cbase + (db + 3) * 1024);
            #pragma unroll
            for (int hh = 0; hh < 2; ++hh) {
                float4 xv[8];
                #pragma unroll
                for (int j = 0; j < 8; ++j)    // broadcasts
                    xv[j] = F4(patch + (hh * 8 + j) * 256 + db);
                #pragma unroll
                for (int j = 0; j < 8; ++j) {
                    fma4(acc[hh * 8 + j], xv[j].x, w0);
                    fma4(acc[hh * 8 + j], xv[j].y, w1);
                    fma4(acc[hh * 8 + j], xv[j].z, w2);
                    fma4(acc[hh * 8 + j], xv[j].w, w3);
                }
            }
        }
        // argmax: per-thread over 4 codes (ascending ids), then 64-lane butterfly
        const int base = cq * 256 + 4 * lane;
        #pragma unroll
        for (int j = 0; j < 16; ++j) {
            float bv = acc[j].x; int bi = base;
            if (acc[j].y > bv) { bv = acc[j].y; bi = base + 1; }
            if (acc[j].z > bv) { bv = acc[j].z; bi = base + 2; }
            if (acc[j].w > bv) { bv = acc[j].w; bi = base + 3; }
            #pragma unroll
            for (int off = 32; off >= 1; off >>= 1) {
                float ov = __shfl_xor(bv, off);
                int   oi = __shfl_xor(bi, off);
                if (ov > bv || (ov == bv && oi < bi)) { bv = ov; bi = oi; }
            }
            if (lane == 0) { rv[cq][j] = bv; ri[cq][j] = bi; }
        }
    }
    __syncthreads();
    if (tid < TPB) {
        float bv = rv[0][tid];
        int   bi = ri[0][tid];
        #pragma unroll
        for (int w = 1; w < 4; ++w) {        // quarters ascending: strict >
            float ov = rv[w][tid];
            if (ov > bv) { bv = ov; bi = ri[w][tid]; }
        }
        out_ind[g0 + tid] = bi;
    }
}

// ---------------------------------------------------------------------------
// embed_len[b] = 8 * min(200, ilens[b] >> 4)
__global__ void len_kernel(const int* __restrict__ ilens, int* __restrict__ out_len) {
    int b = threadIdx.x;
    if (b < Bb) {
        int il = ilens[b];
        int cnt = il >> 4;
        if (cnt > Tp) cnt = Tp;
        if (cnt < 0) cnt = 0;
        out_len[b] = Fp * cnt;
    }
}

// ---------------------------------------------------------------------------
extern "C" void kernel_launch(void* const* d_in, const int* in_sizes, int n_in,
                              void* d_out, int out_size, void* d_ws, size_t ws_size,
                              hipStream_t stream) {
    const float* xs       = (const float*)d_in[0];   // (32,3200,128) f32
    const int*   ilens    = (const int*)  d_in[1];   // (32,) i32
    const float* conv_w   = (const float*)d_in[2];   // (512,1,16,16) f32
    const float* proj     = (const float*)d_in[3];   // (512,256) f32
    const float* codebook = (const float*)d_in[4];   // (1024,256) f32
    int* out = (int*)d_out;                          // 51200 ind + 32 len

    float* wt  = (float*)d_ws;            // 256x512 = 512 KB
    float* cbt = wt + 256 * C;            // 256x1024 = 1 MB
    float* sv  = cbt + 256 * QN;          // 256 colsums = 1 KB

    prep_wt<<<C * 256 / 256, 256, 0, stream>>>(conv_w, wt);
    prep_cb<<<QN, QD, 0, stream>>>(codebook, cbt);
    prep_s<<<1, QD, 0, stream>>>(proj, sv);
    fused_tok<<<TOKS / TPB, 256, 0, stream>>>(xs, wt, proj, cbt, sv, out);
    len_kernel<<<1, 64, 0, stream>>>(ilens, out + TOKS);
}

// Round 9
// 744.784 us; speedup vs baseline: 1.3333x; 1.0609x over previous
//
#include <hip/hip_runtime.h>

#define FBANK_MEAN 15.41663f
#define FBANK_STD  6.55582f

constexpr int Bb   = 32;
constexpr int T    = 3200;
constexpr int D    = 128;
constexpr int C    = 512;    // embed_dim
constexpr int QD   = 256;    // quant_dim
constexpr int QN   = 1024;   // quant_n
constexpr int Tp   = 200;
constexpr int Fp   = 8;
constexpr int NTOK = Tp * Fp;     // 1600 tokens per batch
constexpr int TOKS = Bb * NTOK;   // 51200
constexpr int TPB  = 16;          // tokens per block

// ext_vector float4: whole-vector expressions lower to <4 x float> fmuladd,
// which gfx9xx legalizes as 2x v_pk_fma_f32 (VOP3P packed fp32) -- half the
// VALU issue slots of the struct-float4 componentwise form used before.
typedef float v4fe __attribute__((ext_vector_type(4)));

#define V4(p) (*(const v4fe*)(p))

// ---------------------------------------------------------------------------
// Merged prep (math byte-identical to the 4 separate verified kernels):
// [0,512): transpose conv_w (512x256)->wt(256x512).
// [512,1536): l2-normalize codebook row, store d-major cbt[d*1024+k].
// 1536: proj colsums sv[256] + embed_len.
__global__ void prep_all(const float* __restrict__ w, const float* __restrict__ proj,
                         const float* __restrict__ cb, const int* __restrict__ ilens,
                         float* __restrict__ wt, float* __restrict__ cbt,
                         float* __restrict__ sv, int* __restrict__ out_len) {
    const int bid = blockIdx.x, tid = threadIdx.x;
    if (bid < 512) {
        int idx = bid * 256 + tid;          // idx = k*512 + c
        int k = idx >> 9, c = idx & 511;
        wt[idx] = w[c * 256 + k];
    } else if (bid < 1536) {
        __shared__ float part[4];
        int k = bid - 512;                  // code row
        float v = cb[k * QD + tid];
        float s = v * v;
        #pragma unroll
        for (int off = 32; off >= 1; off >>= 1) s += __shfl_xor(s, off);
        if ((tid & 63) == 0) part[tid >> 6] = s;
        __syncthreads();
        float tot = part[0] + part[1] + part[2] + part[3];
        cbt[tid * QN + k] = v * rsqrtf(tot + 1e-12f);
    } else {
        float acc = 0.f;
        for (int k = 0; k < C; ++k) acc += proj[k * QD + tid];
        sv[tid] = acc;
        if (tid < Bb) {
            int cnt = ilens[tid] >> 4;
            if (cnt > Tp) cnt = Tp;
            if (cnt < 0) cnt = 0;
            out_len[tid] = Fp * cnt;
        }
    }
}

// ---------------------------------------------------------------------------
// Fused: patch -> conv(fp32) -> mean -> proj(fp32, -mu*colsum) ->
//        exact fp32 sims -> argmax.  (Round-4 verified structure; inner
//        loops rewritten on ext_vector float4 for v_pk_fma_f32 codegen.)
// LN rsqrt(var) and xp l2norm are per-token positive scalings -> dropped.
__global__ __launch_bounds__(256, 3) void fused_tok(
    const float* __restrict__ xs,    // B*T*D
    const float* __restrict__ wt,    // 256 x 512 (k-major)
    const float* __restrict__ proj,  // 512 x 256 (k-major)
    const float* __restrict__ cbt,   // 256 x 1024 (d-major, rows l2-normed)
    const float* __restrict__ sv,    // 256 colsum(proj)
    int* __restrict__ out_ind)       // TOKS
{
    __shared__ __align__(16) float patch[TPB * 256];   // 16 KB; reused as xp
    __shared__ __align__(16) float feats[TPB * 512];   // 32 KB
    __shared__ float mu_s[TPB];
    __shared__ float rvs[4][TPB];
    __shared__ int   rif[4][TPB];

    const int tid  = threadIdx.x;
    const int lane = tid & 63;
    const int wv   = tid >> 6;               // wave id 0..3
    const int g0   = blockIdx.x * TPB;
    const int b    = g0 / NTOK;
    const int n0   = g0 - b * NTOK;
    const int tp0  = n0 >> 3;                // first of the two tp rows

    const v4fe zero4 = {0.f, 0.f, 0.f, 0.f};

    // ---- 1. patch staging: 32 time-rows x 128 cols -> patch[t][k] --------
    {
        const v4fe* src = (const v4fe*)(xs + ((size_t)b * T + (size_t)tp0 * 16) * D);
        const float inv = 1.0f / (2.0f * FBANK_STD);
        #pragma unroll
        for (int r = 0; r < 4; ++r) {
            int f4 = r * 256 + tid;          // float4 index 0..1023
            v4fe v = (src[f4] - FBANK_MEAN) * inv;
            int i = f4 >> 5;                 // time row 0..31
            int d = (f4 & 31) << 2;          // fbank col
            int t = ((i >> 4) << 3) + (d >> 4);
            int k = ((i & 15) << 4) + (d & 15);
            *(v4fe*)&patch[t * 256 + k] = v;
        }
    }
    __syncthreads();

    // ---- 2. conv: Mr=16 tok x Nr=4 ch; waves = (ch-half, K-half) ---------
    {
        const int c = wv & 1;                // channel half
        const int h = wv >> 1;               // K half
        v4fe acc[16];
        #pragma unroll
        for (int j = 0; j < 16; ++j) acc[j] = zero4;
        const float* wb = wt + c * 256 + 4 * lane;
        for (int k4 = 0; k4 < 32; ++k4) {
            const int kb = h * 128 + k4 * 4;
            v4fe w0 = V4(wb + (kb + 0) * 512);
            v4fe w1 = V4(wb + (kb + 1) * 512);
            v4fe w2 = V4(wb + (kb + 2) * 512);
            v4fe w3 = V4(wb + (kb + 3) * 512);
            #pragma unroll
            for (int hh = 0; hh < 2; ++hh) {
                v4fe xv[8];
                #pragma unroll
                for (int j = 0; j < 8; ++j)    // wave-uniform broadcasts
                    xv[j] = V4(patch + (hh * 8 + j) * 256 + kb);
                #pragma unroll
                for (int j = 0; j < 8; ++j) {
                    acc[hh * 8 + j] += xv[j].x * w0;
                    acc[hh * 8 + j] += xv[j].y * w1;
                    acc[hh * 8 + j] += xv[j].z * w2;
                    acc[hh * 8 + j] += xv[j].w * w3;
                }
            }
        }
        float* fb0 = &feats[c * 256 + 4 * lane];
        if (h == 0) {
            #pragma unroll
            for (int j = 0; j < 16; ++j)
                *(v4fe*)(fb0 + j * 512) = acc[j];
        }
        __syncthreads();
        if (h == 1) {
            #pragma unroll
            for (int j = 0; j < 16; ++j) {
                v4fe o = V4(fb0 + j * 512);
                o += acc[j];
                *(v4fe*)(fb0 + j * 512) = o;
            }
        }
    }
    __syncthreads();

    // ---- 3. per-token mean of feats (var scaling is argmax-invariant) ----
    {
        const int t = tid >> 4, l = tid & 15;
        float s1 = 0.f;
        #pragma unroll
        for (int m = 0; m < 32; ++m) s1 += feats[t * 512 + l + 16 * m];
        #pragma unroll
        for (int off = 8; off >= 1; off >>= 1) s1 += __shfl_xor(s1, off);
        if (l == 0) mu_s[t] = s1 * (1.0f / 512.0f);
    }
    __syncthreads();

    // ---- 4. proj: Mr=8 tok x Nr=4 qd; waves = (tok-half, K-half) ---------
    {
        const int g = wv & 1;                // token half
        const int h = wv >> 1;               // K half (256 each)
        v4fe acc[8];
        #pragma unroll
        for (int j = 0; j < 8; ++j) acc[j] = zero4;
        const float* pb = proj + 4 * lane;
        const float* fb0 = &feats[(g * 8) * 512];
        for (int k4 = 0; k4 < 64; ++k4) {
            const int kb = h * 256 + k4 * 4;
            v4fe w0 = V4(pb + (kb + 0) * 256);
            v4fe w1 = V4(pb + (kb + 1) * 256);
            v4fe w2 = V4(pb + (kb + 2) * 256);
            v4fe w3 = V4(pb + (kb + 3) * 256);
            v4fe xv[8];
            #pragma unroll
            for (int j = 0; j < 8; ++j)        // broadcasts
                xv[j] = V4(fb0 + j * 512 + kb);
            #pragma unroll
            for (int j = 0; j < 8; ++j) {
                acc[j] += xv[j].x * w0;
                acc[j] += xv[j].y * w1;
                acc[j] += xv[j].z * w2;
                acc[j] += xv[j].w * w3;
            }
        }
        float* xb = &patch[(g * 8) * 256 + 4 * lane];   // patch region = xp now
        if (h == 0) {                        // epilogue: y - mu * colsum(proj)
            v4fe s4 = V4(sv + 4 * lane);
            #pragma unroll
            for (int j = 0; j < 8; ++j) {
                v4fe o = acc[j] - mu_s[g * 8 + j] * s4;
                *(v4fe*)(xb + j * 256) = o;
            }
        }
        __syncthreads();
        if (h == 1) {
            #pragma unroll
            for (int j = 0; j < 8; ++j) {
                v4fe o = V4(xb + j * 256);
                o += acc[j];
                *(v4fe*)(xb + j * 256) = o;
            }
        }
    }
    __syncthreads();

    // ---- 5. sims: Mr=16 tok x Nr=4 codes; waves = code-quarters ----------
    {
        const int cq = wv;                   // code quarter
        v4fe acc[16];
        #pragma unroll
        for (int j = 0; j < 16; ++j) acc[j] = zero4;
        const float* cbase = cbt + cq * 256 + 4 * lane;
        for (int d4 = 0; d4 < 64; ++d4) {
            const int db = d4 * 4;
            v4fe w0 = V4(cbase + (db + 0) * 1024);
            v4fe w1 = V4(cbase + (db + 1) * 1024);
            v4fe w2 = V4(cbase + (db + 2) * 1024);
            v4fe w3 = V4(cbase + (db + 3) * 1024);
            #pragma unroll
            for (int hh = 0; hh < 2; ++hh) {
                v4fe xv[8];
                #pragma unroll
                for (int j = 0; j < 8; ++j)    // broadcasts
                    xv[j] = V4(patch + (hh * 8 + j) * 256 + db);
                #pragma unroll
                for (int j = 0; j < 8; ++j) {
                    acc[hh * 8 + j] += xv[j].x * w0;
                    acc[hh * 8 + j] += xv[j].y * w1;
                    acc[hh * 8 + j] += xv[j].z * w2;
                    acc[hh * 8 + j] += xv[j].w * w3;
                }
            }
        }
        // argmax: per-thread over 4 codes (ascending ids), 64-lane butterfly
        const int base = cq * 256 + 4 * lane;
        #pragma unroll
        for (int j = 0; j < 16; ++j) {
            float bv = acc[j].x; int bi = base;
            if (acc[j].y > bv) { bv = acc[j].y; bi = base + 1; }
            if (acc[j].z > bv) { bv = acc[j].z; bi = base + 2; }
            if (acc[j].w > bv) { bv = acc[j].w; bi = base + 3; }
            #pragma unroll
            for (int off = 32; off >= 1; off >>= 1) {
                float ov = __shfl_xor(bv, off);
                int   oi = __shfl_xor(bi, off);
                if (ov > bv || (ov == bv && oi < bi)) { bv = ov; bi = oi; }
            }
            if (lane == 0) { rvs[cq][j] = bv; rif[cq][j] = bi; }
        }
    }
    __syncthreads();
    if (tid < TPB) {
        float bv = rvs[0][tid];
        int   bi = rif[0][tid];
        #pragma unroll
        for (int w = 1; w < 4; ++w) {        // quarters ascending: strict >
            float ov = rvs[w][tid];
            if (ov > bv) { bv = ov; bi = rif[w][tid]; }
        }
        out_ind[g0 + tid] = bi;
    }
}

// ---------------------------------------------------------------------------
extern "C" void kernel_launch(void* const* d_in, const int* in_sizes, int n_in,
                              void* d_out, int out_size, void* d_ws, size_t ws_size,
                              hipStream_t stream) {
    const float* xs       = (const float*)d_in[0];   // (32,3200,128) f32
    const int*   ilens    = (const int*)  d_in[1];   // (32,) i32
    const float* conv_w   = (const float*)d_in[2];   // (512,1,16,16) f32
    const float* proj     = (const float*)d_in[3];   // (512,256) f32
    const float* codebook = (const float*)d_in[4];   // (1024,256) f32
    int* out = (int*)d_out;                          // 51200 ind + 32 len

    // Workspace footprint identical to passing rounds 2-4: 1.501 MB.
    float* wt  = (float*)d_ws;            // 256x512 = 512 KB
    float* cbt = wt + 256 * C;            // 256x1024 = 1 MB
    float* sv  = cbt + QD * QN;           // 256 floats = 1 KB

    prep_all<<<1537, 256, 0, stream>>>(conv_w, proj, codebook, ilens,
                                       wt, cbt, sv, out + TOKS);
    fused_tok<<<TOKS / TPB, 256, 0, stream>>>(xs, wt, proj, cbt, sv, out);
}